// Round 7
// baseline (323.412 us; speedup 1.0000x reference)
//
#include <hip/hip_runtime.h>

#define DIM   64
#define KCB   1024
#define RPB   256
#define QCAP  192      // per-wave queue (16 rows/wave -> 12/row margin), u16 items

// dynamic LDS layout (float words):
//  xs     [16384]               swizzled x (word = row*64 + ((cj^(row&15))<<2))
//  Atab   [256]  @16384
//  Ttab   [256]  @16640         (reused as dtab for the loss tree)
//  csq_s  [1024] @16896
//  keytab [256 u64] @17920 (512 words)
//  qcnt   [16 int] @18432
//  ovfl   @18448
//  qbuf   u16[16][QCAP] @18449  (1536 words at QCAP=192)
#define SMEM_WORDS (18449 + (16 * QCAP) / 2)
#define SMEM_BYTES (SMEM_WORDS * 4)   // 79,940 B -> 2 blocks/CU (159,880 <= 163,840)

// ws layout (floats): ws[0] = loss acc; ws[256..1279] = csq[k];
//                     ws[2048..] = cb_hi bf16 [1024][64] (32768 float slots)
#define WS_NEED_BYTES ((2048 + 32768) * 4)

typedef __attribute__((ext_vector_type(8))) short short8;
typedef __attribute__((ext_vector_type(4))) float f32x4;

__device__ __forceinline__ unsigned short f2bf(float f) {
    union { float f; unsigned u; } v; v.f = f;
    unsigned u = v.u;
    return (unsigned short)((u + 0x7FFFu + ((u >> 16) & 1u)) >> 16);  // RNE
}

__global__ void vq_prep(const float* __restrict__ cb, float* __restrict__ ws, int do_bf) {
    int k = blockIdx.x * blockDim.x + threadIdx.x;
    if (k < KCB) {
        const float4* e4 = (const float4*)(cb + (k << 6));
        float4 xq[16];
        #pragma unroll
        for (int j = 0; j < 16; ++j) xq[j] = e4[j];
        {
            #pragma clang fp contract(off)
            float racc[8];
            racc[0]=xq[0].x*xq[0].x; racc[1]=xq[0].y*xq[0].y;
            racc[2]=xq[0].z*xq[0].z; racc[3]=xq[0].w*xq[0].w;
            racc[4]=xq[1].x*xq[1].x; racc[5]=xq[1].y*xq[1].y;
            racc[6]=xq[1].z*xq[1].z; racc[7]=xq[1].w*xq[1].w;
            #pragma unroll
            for (int t = 1; t < 8; ++t) {
                float4 a = xq[2*t], b = xq[2*t+1];
                racc[0]+=a.x*a.x; racc[1]+=a.y*a.y; racc[2]+=a.z*a.z; racc[3]+=a.w*a.w;
                racc[4]+=b.x*b.x; racc[5]+=b.y*b.y; racc[6]+=b.z*b.z; racc[7]+=b.w*b.w;
            }
            ws[256 + k] = ((racc[0] + racc[1]) + (racc[2] + racc[3]))
                        + ((racc[4] + racc[5]) + (racc[6] + racc[7]));
        }
        if (do_bf) {
            short8* dst = (short8*)((unsigned short*)(ws + 2048) + (k << 6));
            #pragma unroll
            for (int p = 0; p < 8; ++p) {
                float4 v = xq[2*p], u = xq[2*p+1];
                short8 s;
                s[0]=(short)f2bf(v.x); s[1]=(short)f2bf(v.y);
                s[2]=(short)f2bf(v.z); s[3]=(short)f2bf(v.w);
                s[4]=(short)f2bf(u.x); s[5]=(short)f2bf(u.y);
                s[6]=(short)f2bf(u.z); s[7]=(short)f2bf(u.w);
                dst[p] = s;
            }
        }
    }
    if (k == 0) ws[0] = 0.0f;
}

// Two-pass MFMA-filtered VQ — 1024 thr (16 waves x 16 rows), full occupancy:
//  - 2 blocks/CU x 16 waves = 32 waves/CU = 8 waves/SIMD (R6 had 4): TLP hides
//    the per-iter L2 load latency that the compiler-defeated prefetch couldn't.
//  - no register prefetch; per-wave live set ~55 VGPR < the 64 cap at 8 w/SIMD.
//  - all fp chains / orders / flag semantics / 256-leaf loss tree verbatim R6.
__global__ __launch_bounds__(1024, 2) void vq_mfma(
        const float* __restrict__ in,
        const float* __restrict__ cb,
        float* __restrict__ ws,
        float* __restrict__ codes_f,
        float* __restrict__ out)
{
    extern __shared__ float smem[];
    float* xs    = smem;
    float* Atab  = smem + 16384;
    float* Ttab  = smem + 16640;                       // reused as dtab
    float* csq_s = smem + 16896;
    unsigned long long* keytab = (unsigned long long*)(smem + 17920);
    int* qcnt  = (int*)(smem + 18432);                 // [16]
    int* ovflp = (int*)(smem + 18448);
    unsigned short* qbuf = (unsigned short*)(smem + 18449);  // [16][QCAP]

    const int tid  = threadIdx.x;
    const int lane = tid & 63;
    const int w    = tid >> 6;                         // wave 0..15
    const int r    = lane & 15;
    const int g    = lane >> 4;
    const int wrow = w << 4;                           // 16 rows per wave
    const size_t rowBase = (size_t)blockIdx.x * RPB;
    const float* csq = ws + 256;
    const unsigned short* cbh = (const unsigned short*)(ws + 2048);
    float* loss_acc = ws;

    // ---- stage x once (swizzled), csq, init tabs ----
    {
        const float4* gx = (const float4*)(in + rowBase * DIM);
        #pragma unroll
        for (int i = 0; i < 4; ++i) {
            int idx = i * 1024 + tid;
            int row = idx >> 4, cj = idx & 15;
            float4 v = gx[idx];
            *(float4*)(xs + row * 64 + ((cj ^ (row & 15)) << 2)) = v;
        }
    }
    if (tid < KCB) csq_s[tid] = csq[tid];
    if (tid < RPB) keytab[tid] = 0xFFFFFFFFFFFFFFFFull;
    if (tid < 16) qcnt[tid] = 0;
    if (tid == 0) *ovflp = 0;
    __syncthreads();

    // ---- per-row A (exact pairwise-8 order), S1, tau (row = tid; from LDS) ----
    if (tid < RPB) {
        const float* xr = xs + tid * 64;
        const int s = tid & 15;
        float A, S1;
        {
            #pragma clang fp contract(off)
            float racc[8], sacc[8];
            {
                float4 a = *(const float4*)(xr + ((0 ^ s) << 2));
                float4 b = *(const float4*)(xr + ((1 ^ s) << 2));
                racc[0]=a.x*a.x; racc[1]=a.y*a.y; racc[2]=a.z*a.z; racc[3]=a.w*a.w;
                racc[4]=b.x*b.x; racc[5]=b.y*b.y; racc[6]=b.z*b.z; racc[7]=b.w*b.w;
                sacc[0]=__builtin_fabsf(a.x); sacc[1]=__builtin_fabsf(a.y);
                sacc[2]=__builtin_fabsf(a.z); sacc[3]=__builtin_fabsf(a.w);
                sacc[4]=__builtin_fabsf(b.x); sacc[5]=__builtin_fabsf(b.y);
                sacc[6]=__builtin_fabsf(b.z); sacc[7]=__builtin_fabsf(b.w);
            }
            #pragma unroll
            for (int t = 1; t < 8; ++t) {
                float4 a = *(const float4*)(xr + (((2*t)   ^ s) << 2));
                float4 b = *(const float4*)(xr + (((2*t+1) ^ s) << 2));
                racc[0]+=a.x*a.x; racc[1]+=a.y*a.y; racc[2]+=a.z*a.z; racc[3]+=a.w*a.w;
                racc[4]+=b.x*b.x; racc[5]+=b.y*b.y; racc[6]+=b.z*b.z; racc[7]+=b.w*b.w;
                sacc[0]+=__builtin_fabsf(a.x); sacc[1]+=__builtin_fabsf(a.y);
                sacc[2]+=__builtin_fabsf(a.z); sacc[3]+=__builtin_fabsf(a.w);
                sacc[4]+=__builtin_fabsf(b.x); sacc[5]+=__builtin_fabsf(b.y);
                sacc[6]+=__builtin_fabsf(b.z); sacc[7]+=__builtin_fabsf(b.w);
            }
            A  = ((racc[0]+racc[1])+(racc[2]+racc[3]))
               + ((racc[4]+racc[5])+(racc[6]+racc[7]));
            S1 = ((sacc[0]+sacc[1])+(sacc[2]+sacc[3]))
               + ((sacc[4]+sacc[5])+(sacc[6]+sacc[7]));
        }
        Atab[tid] = A;
        Ttab[tid] = 1.52587890625e-05f * S1
                  + 4.76837158203125e-07f * (A + 1.0f)
                  + 1e-5f;                             // certified >= 2E (R2-R6 verified)
    }

    // ---- A-fragments (bf16 hi of x) from LDS (row = wrow + r) ----
    short8 af[2];
    #pragma unroll
    for (int h = 0; h < 2; ++h) {
        const int row = wrow + r;                      // row&15 == r
        const int cj = h*8 + g*2;
        float4 v0 = *(const float4*)(xs + row*64 + (((cj  ) ^ r) << 2));
        float4 v1 = *(const float4*)(xs + row*64 + (((cj+1) ^ r) << 2));
        short8 a;
        a[0]=(short)f2bf(v0.x); a[1]=(short)f2bf(v0.y);
        a[2]=(short)f2bf(v0.z); a[3]=(short)f2bf(v0.w);
        a[4]=(short)f2bf(v1.x); a[5]=(short)f2bf(v1.y);
        a[6]=(short)f2bf(v1.z); a[7]=(short)f2bf(v1.w);
        af[h] = a;
    }

    __syncthreads();

    // ---- PASS 1: per-lane running max only ----
    float rm[4];
    #pragma unroll
    for (int s = 0; s < 4; ++s) rm[s] = -3.402823466e38f;

    #pragma unroll 1
    for (int nb = 0; nb < KCB; nb += 32) {
        short8 bcur[2][2];
        #pragma unroll
        for (int nt = 0; nt < 2; ++nt)
            #pragma unroll
            for (int h = 0; h < 2; ++h)
                bcur[nt][h] = *(const short8*)(cbh + ((nb + nt*16 + r) << 6) + h*32 + g*8);

        float csqh[2];
        #pragma unroll
        for (int nt = 0; nt < 2; ++nt) csqh[nt] = -0.5f * csq_s[nb + nt*16 + r];

        f32x4 acc[2];
        #pragma unroll
        for (int nt = 0; nt < 2; ++nt) {
            f32x4 c; c[0]=csqh[nt]; c[1]=csqh[nt]; c[2]=csqh[nt]; c[3]=csqh[nt];
            acc[nt] = c;
        }
        #pragma unroll
        for (int h = 0; h < 2; ++h)
            #pragma unroll
            for (int nt = 0; nt < 2; ++nt)
                acc[nt] = __builtin_amdgcn_mfma_f32_16x16x32_bf16(
                    af[h], bcur[nt][h], acc[nt], 0, 0, 0);

        #pragma unroll
        for (int rg = 0; rg < 4; ++rg) {
            float cm = fmaxf(acc[0][rg], acc[1][rg]);
            rm[rg] = fmaxf(rm[rg], cm);
        }
    }

    // ---- one cross-lane reduce (over r bits) -> final per-row threshold ----
    float thr[4];
    #pragma unroll
    for (int s = 0; s < 4; ++s) {
        float cm = rm[s];
        cm = fmaxf(cm, __shfl_xor(cm, 1));
        cm = fmaxf(cm, __shfl_xor(cm, 2));
        cm = fmaxf(cm, __shfl_xor(cm, 4));
        cm = fmaxf(cm, __shfl_xor(cm, 8));
        thr[s] = cm - Ttab[wrow + g*4 + s];
    }

    // ---- PASS 2: recompute (bit-identical) + ballot-compacted flagging ----
    #pragma unroll 1
    for (int nb = 0; nb < KCB; nb += 32) {
        short8 bcur[2][2];
        #pragma unroll
        for (int nt = 0; nt < 2; ++nt)
            #pragma unroll
            for (int h = 0; h < 2; ++h)
                bcur[nt][h] = *(const short8*)(cbh + ((nb + nt*16 + r) << 6) + h*32 + g*8);

        float csqh[2];
        #pragma unroll
        for (int nt = 0; nt < 2; ++nt) csqh[nt] = -0.5f * csq_s[nb + nt*16 + r];

        f32x4 acc[2];
        #pragma unroll
        for (int nt = 0; nt < 2; ++nt) {
            f32x4 c; c[0]=csqh[nt]; c[1]=csqh[nt]; c[2]=csqh[nt]; c[3]=csqh[nt];
            acc[nt] = c;
        }
        #pragma unroll
        for (int h = 0; h < 2; ++h)
            #pragma unroll
            for (int nt = 0; nt < 2; ++nt)
                acc[nt] = __builtin_amdgcn_mfma_f32_16x16x32_bf16(
                    af[h], bcur[nt][h], acc[nt], 0, 0, 0);

        #pragma unroll
        for (int rg = 0; rg < 4; ++rg) {
            const float th = thr[rg];
            const bool f0 = acc[0][rg] >= th;
            const bool f1 = acc[1][rg] >= th;
            if (__ballot(f0 | f1)) {                   // uniform coarse skip
                const int rowLocal = g*4 + rg;         // 0..15 within wave
                #pragma unroll
                for (int nt = 0; nt < 2; ++nt) {
                    const bool fl = (nt==0) ? f0 : f1;
                    unsigned long long m = __ballot(fl);
                    if (m) {
                        int base = 0;
                        if (lane == 0) base = atomicAdd(&qcnt[w], (int)__popcll(m));
                        base = __builtin_amdgcn_readfirstlane(base);
                        if (fl) {
                            int pos = base + (int)__popcll(m & ((1ull << lane) - 1ull));
                            if (pos < QCAP)
                                qbuf[w * QCAP + pos] =
                                    (unsigned short)((rowLocal << 10) | (nb + nt*16 + r));
                            else *ovflp = 1;
                        }
                    }
                }
            }
        }
    }

    // ---- batched exact rescore (x from LDS, bit-identical) + atomicMin merge ----
    const int cnt  = qcnt[w];
    const int cmax = cnt < QCAP ? cnt : QCAP;
    for (int base = 0; base < cmax; base += 64) {
        const int i = base + lane;
        if (i < cmax) {
            const int item = qbuf[w * QCAP + i];
            const int row = wrow + (item >> 10);
            const int n = item & 1023;
            const float* xr = xs + row * 64;
            const int sr = row & 15;
            const float4* e4 = (const float4*)(cb + ((size_t)n << 6));
            float mm = 0.f;
            #pragma unroll
            for (int j = 0; j < 16; ++j) {
                float4 xq = *(const float4*)(xr + ((j ^ sr) << 2));
                float4 eq = e4[j];
                mm = __builtin_fmaf(xq.x, eq.x, mm);
                mm = __builtin_fmaf(xq.y, eq.y, mm);
                mm = __builtin_fmaf(xq.z, eq.z, mm);
                mm = __builtin_fmaf(xq.w, eq.w, mm);
            }
            float dd;
            {
                #pragma clang fp contract(off)
                dd = (Atab[row] - 2.0f * mm) + csq_s[n];
            }
            unsigned long long key =
                ((unsigned long long)__float_as_uint(dd) << 32) | (unsigned)n;
            atomicMin(&keytab[row], key);
        }
    }
    __syncthreads();

    // ---- per-row result, overflow fallback, code publish ----
    float* dtab = Ttab;                                // Ttab dead past thr computation
    if (tid < RPB) {
        unsigned long long kk = keytab[tid];
        int   kb = (int)(kk & 1023u);
        float db = __uint_as_float((unsigned)(kk >> 32));
        if (*ovflp) {   // practically unreachable; exact full scan
            const float* xr = in + (rowBase + tid) * (size_t)DIM;
            float dmin = 3.402823466e38f; int kmin = 0;
            for (int n = 0; n < KCB; ++n) {
                const float* eg = cb + ((size_t)n << 6);
                float mmv = 0.f;
                for (int j = 0; j < 64; ++j) mmv = __builtin_fmaf(xr[j], eg[j], mmv);
                float ddv;
                {
                    #pragma clang fp contract(off)
                    ddv = (Atab[tid] - 2.0f * mmv) + csq_s[n];
                }
                if (ddv < dmin) { dmin = ddv; kmin = n; }
            }
            db = dmin; kb = kmin;
        }
        dtab[tid] = db;
        codes_f[rowBase + tid] = (float)kb;
        keytab[tid] = (unsigned long long)(unsigned)kb;   // publish code for ST pass
    }
    __syncthreads();

    // ---- fused straight-through write: st = x + (q - x), x from LDS ----
    {
        float4* gout = (float4*)(out + rowBase * DIM);
        #pragma unroll
        for (int i = 0; i < 4; ++i) {
            int idx = i * 1024 + tid;
            int row = idx >> 4, cj = idx & 15;
            int code = (int)keytab[row];
            float4 qv = *(const float4*)(cb + ((size_t)code << 6) + (cj << 2));
            float4 xv = *(const float4*)(xs + row * 64 + ((cj ^ (row & 15)) << 2));
            float4 st;
            {
                #pragma clang fp contract(off)
                st.x = xv.x + (qv.x - xv.x);
                st.y = xv.y + (qv.y - xv.y);
                st.z = xv.z + (qv.z - xv.z);
                st.w = xv.w + (qv.w - xv.w);
            }
            gout[idx] = st;
        }
    }

    // ---- loss partial (identical 256-leaf tree) ----
    __syncthreads();
    #pragma unroll
    for (int s = 128; s > 0; s >>= 1) {
        if (tid < s) dtab[tid] += dtab[tid + s];
        __syncthreads();
    }
    if (tid == 0) atomicAdd(loss_acc, dtab[0]);
}

// ===================== fallback: R1 scalar kernel (used only if ws too small) ==========
#define OLD_SMEM_WORDS 20480
#define OLD_SMEM_BYTES (OLD_SMEM_WORDS * 4)

__global__ __launch_bounds__(512, 4) void vq_main_old(
        const float* __restrict__ in,
        const float* __restrict__ cb,
        const float* __restrict__ csq,
        float* __restrict__ codes_f,
        float* __restrict__ out,
        float* __restrict__ loss_acc)
{
    extern __shared__ float smem[];
    float* xs    = smem;
    float* dtab  = smem + 16384;
    int*   ktab  = (int*)(smem + 18432);

    const int tid  = threadIdx.x;
    const int lane = tid & 63;
    const int q    = __builtin_amdgcn_readfirstlane(tid >> 6);
    const size_t rowBase = (size_t)blockIdx.x * RPB;

    {
        const float4* gx = (const float4*)(in + rowBase * DIM);
        #pragma unroll
        for (int i = 0; i < 8; ++i) {
            int idx = i * 512 + tid;
            int row = idx >> 4, cj = idx & 15;
            float4 v = gx[idx];
            *(float4*)(xs + row * 64 + ((cj ^ (row & 15)) << 2)) = v;
        }
    }
    __syncthreads();

    float A[4];
    #pragma unroll
    for (int ri = 0; ri < 4; ++ri) {
        const int row = lane + (ri << 6);
        float xv[64];
        #pragma unroll
        for (int cj = 0; cj < 16; ++cj) {
            float4 v = *(const float4*)(xs + row * 64 + ((cj ^ (lane & 15)) << 2));
            xv[cj*4+0]=v.x; xv[cj*4+1]=v.y; xv[cj*4+2]=v.z; xv[cj*4+3]=v.w;
        }
        {
            #pragma clang fp contract(off)
            float racc[8];
            #pragma unroll
            for (int j = 0; j < 8; ++j) racc[j] = xv[j] * xv[j];
            #pragma unroll
            for (int t = 1; t < 8; ++t) {
                #pragma unroll
                for (int j = 0; j < 8; ++j) racc[j] += xv[8*t+j] * xv[8*t+j];
            }
            A[ri] = ((racc[0] + racc[1]) + (racc[2] + racc[3]))
                  + ((racc[4] + racc[5]) + (racc[6] + racc[7]));
        }
    }

    const float* cbq   = cb  + ((size_t)q << 13);
    const float* csq_q = csq + (q << 7);
    float dmin[4] = {3.402823466e38f, 3.402823466e38f, 3.402823466e38f, 3.402823466e38f};
    int   kmin[4] = {0, 0, 0, 0};
    const int xb = lane * 64;

    #pragma unroll 1
    for (int ke = 0; ke < 128; ke += 16) {
        float m[4][16];
        #pragma unroll
        for (int ri = 0; ri < 4; ++ri)
            #pragma unroll
            for (int e = 0; e < 16; ++e) m[ri][e] = 0.0f;

        #pragma unroll 1
        for (int jb = 0; jb < 64; jb += 4) {
            const int slot4 = ((jb >> 2) ^ (lane & 15)) << 2;
            float4 a0 = *(const float4*)(xs + xb +         slot4);
            float4 a1 = *(const float4*)(xs + xb +  4096 + slot4);
            float4 a2 = *(const float4*)(xs + xb +  8192 + slot4);
            float4 a3 = *(const float4*)(xs + xb + 12288 + slot4);
            #pragma unroll
            for (int e = 0; e < 16; ++e) {
                float4 ev = *(const float4*)(cbq + ((ke + e) << 6) + jb);
                m[0][e] = __builtin_fmaf(a0.x, ev.x, m[0][e]);
                m[0][e] = __builtin_fmaf(a0.y, ev.y, m[0][e]);
                m[0][e] = __builtin_fmaf(a0.z, ev.z, m[0][e]);
                m[0][e] = __builtin_fmaf(a0.w, ev.w, m[0][e]);
                m[1][e] = __builtin_fmaf(a1.x, ev.x, m[1][e]);
                m[1][e] = __builtin_fmaf(a1.y, ev.y, m[1][e]);
                m[1][e] = __builtin_fmaf(a1.z, ev.z, m[1][e]);
                m[1][e] = __builtin_fmaf(a1.w, ev.w, m[1][e]);
                m[2][e] = __builtin_fmaf(a2.x, ev.x, m[2][e]);
                m[2][e] = __builtin_fmaf(a2.y, ev.y, m[2][e]);
                m[2][e] = __builtin_fmaf(a2.z, ev.z, m[2][e]);
                m[2][e] = __builtin_fmaf(a2.w, ev.w, m[2][e]);
                m[3][e] = __builtin_fmaf(a3.x, ev.x, m[3][e]);
                m[3][e] = __builtin_fmaf(a3.y, ev.y, m[3][e]);
                m[3][e] = __builtin_fmaf(a3.z, ev.z, m[3][e]);
                m[3][e] = __builtin_fmaf(a3.w, ev.w, m[3][e]);
            }
        }

        #pragma unroll
        for (int e = 0; e < 16; ++e) {
            float cse = csq_q[ke + e];
            int gk = (q << 7) + ke + e;
            #pragma unroll
            for (int ri = 0; ri < 4; ++ri) {
                float d;
                {
                    #pragma clang fp contract(off)
                    d = (A[ri] - 2.0f * m[ri][e]) + cse;
                }
                if (d < dmin[ri]) { dmin[ri] = d; kmin[ri] = gk; }
            }
        }
    }

    #pragma unroll
    for (int ri = 0; ri < 4; ++ri) {
        int row = lane + (ri << 6);
        dtab[row * 8 + q] = dmin[ri];
        ktab[row * 8 + q] = kmin[ri];
    }
    __syncthreads();

    float db = 0.0f;
    if (tid < RPB) {
        db = dtab[tid * 8];
        int kb = ktab[tid * 8];
        #pragma unroll
        for (int qq = 1; qq < 8; ++qq) {
            float dq = dtab[tid * 8 + qq];
            int   kq = ktab[tid * 8 + qq];
            if (dq < db) { db = dq; kb = kq; }
        }
        ktab[tid * 8] = kb;
        codes_f[rowBase + tid] = (float)kb;
    }
    __syncthreads();

    {
        float4* gout = (float4*)(out + rowBase * DIM);
        #pragma unroll
        for (int i = 0; i < 8; ++i) {
            int idx = i * 512 + tid;
            int row = idx >> 4, cj = idx & 15;
            int code = ktab[row * 8];
            float4 qv = *(const float4*)(cb + ((size_t)code << 6) + (cj << 2));
            float4 xv = *(const float4*)(xs + row * 64 + ((cj ^ (row & 15)) << 2));
            float4 st;
            {
                #pragma clang fp contract(off)
                st.x = xv.x + (qv.x - xv.x);
                st.y = xv.y + (qv.y - xv.y);
                st.z = xv.z + (qv.z - xv.z);
                st.w = xv.w + (qv.w - xv.w);
            }
            gout[idx] = st;
        }
    }

    if (tid < RPB) dtab[tid] = db;
    __syncthreads();
    #pragma unroll
    for (int s = 128; s > 0; s >>= 1) {
        if (tid < s) dtab[tid] += dtab[tid + s];
        __syncthreads();
    }
    if (tid == 0) atomicAdd(loss_acc, dtab[0]);
}

__global__ void vq_final(const float* __restrict__ ws, float* __restrict__ loss_out) {
    loss_out[0] = 1.25f * ws[0] / 8388608.0f;
}

extern "C" void kernel_launch(void* const* d_in, const int* in_sizes, int n_in,
                              void* d_out, int out_size, void* d_ws, size_t ws_size,
                              hipStream_t stream) {
    const float* in = (const float*)d_in[0];   // (32,4096,64) fp32
    const float* cb = (const float*)d_in[1];   // (1024,64)    fp32
    float* out     = (float*)d_out;
    float* codes_f = out + 8388608;
    float* loss_p  = out + 8519680;
    float* ws      = (float*)d_ws;

    const int big = (ws_size >= (size_t)WS_NEED_BYTES) ? 1 : 0;

    vq_prep<<<16, 64, 0, stream>>>(cb, ws, big);
    if (big) {
        hipFuncSetAttribute((const void*)vq_mfma,
                            hipFuncAttributeMaxDynamicSharedMemorySize, SMEM_BYTES);
        vq_mfma<<<512, 1024, SMEM_BYTES, stream>>>(in, cb, ws, codes_f, out);
    } else {
        hipFuncSetAttribute((const void*)vq_main_old,
                            hipFuncAttributeMaxDynamicSharedMemorySize, OLD_SMEM_BYTES);
        vq_main_old<<<512, 512, OLD_SMEM_BYTES, stream>>>(in, cb, ws + 256, codes_f, out, ws);
    }
    vq_final<<<1, 1, 0, stream>>>(ws, loss_p);
}

// Round 9
// 161.058 us; speedup vs baseline: 2.0080x; 2.0080x over previous
//
#include <hip/hip_runtime.h>

#define DIM   64
#define KCB   1024
#define RPB   256
#define QCAP  192      // per-wave queue (16 rows/wave -> 12/row margin), u16 items
#define BCH   128      // codebook entries staged per barrier-chunk (16 KB bf16)

// dynamic LDS layout (float words):
//  xs     [16384]               swizzled x (word = row*64 + ((cj^(row&15))<<2))
//  Atab   [256]  @16384
//  Ttab   [256]  @16640         (reused as dtab for the loss tree)
//  csq_s  [1024] @16896
//  keytab [256 u64] @17920 (512 words)
//  qcnt   [16 int] @18432
//  ovfl   @18448
//  qbuf   u16[16][QCAP] @18449  (16*192 u16 = 1536 WORDS) -> ends 19985
//  bsh    @19988 (16B-aligned, PAST qbuf -- R8 overlapped here and corrupted
//                 waves 8-15's queue): BCH entries x 32 words, granule-swizzled
//                 (granule j of entry c stored at slot j^(c&7))
#define BSH_OFS 19988
#define SMEM_WORDS (BSH_OFS + BCH * 32)     // 24084 words = 96,336 B -> 1 block/CU
#define SMEM_BYTES (SMEM_WORDS * 4)

// ws layout (floats): ws[0] = loss acc; ws[256..1279] = csq[k];
//                     ws[2048..] = cb_hi bf16 [1024][64] (32768 float slots)
#define WS_NEED_BYTES ((2048 + 32768) * 4)

typedef __attribute__((ext_vector_type(8))) short short8;
typedef __attribute__((ext_vector_type(4))) float f32x4;

__device__ __forceinline__ unsigned short f2bf(float f) {
    union { float f; unsigned u; } v; v.f = f;
    unsigned u = v.u;
    return (unsigned short)((u + 0x7FFFu + ((u >> 16) & 1u)) >> 16);  // RNE
}

__global__ void vq_prep(const float* __restrict__ cb, float* __restrict__ ws, int do_bf) {
    int k = blockIdx.x * blockDim.x + threadIdx.x;
    if (k < KCB) {
        const float4* e4 = (const float4*)(cb + (k << 6));
        float4 xq[16];
        #pragma unroll
        for (int j = 0; j < 16; ++j) xq[j] = e4[j];
        {
            #pragma clang fp contract(off)
            float racc[8];
            racc[0]=xq[0].x*xq[0].x; racc[1]=xq[0].y*xq[0].y;
            racc[2]=xq[0].z*xq[0].z; racc[3]=xq[0].w*xq[0].w;
            racc[4]=xq[1].x*xq[1].x; racc[5]=xq[1].y*xq[1].y;
            racc[6]=xq[1].z*xq[1].z; racc[7]=xq[1].w*xq[1].w;
            #pragma unroll
            for (int t = 1; t < 8; ++t) {
                float4 a = xq[2*t], b = xq[2*t+1];
                racc[0]+=a.x*a.x; racc[1]+=a.y*a.y; racc[2]+=a.z*a.z; racc[3]+=a.w*a.w;
                racc[4]+=b.x*b.x; racc[5]+=b.y*b.y; racc[6]+=b.z*b.z; racc[7]+=b.w*b.w;
            }
            ws[256 + k] = ((racc[0] + racc[1]) + (racc[2] + racc[3]))
                        + ((racc[4] + racc[5]) + (racc[6] + racc[7]));
        }
        if (do_bf) {
            short8* dst = (short8*)((unsigned short*)(ws + 2048) + (k << 6));
            #pragma unroll
            for (int p = 0; p < 8; ++p) {
                float4 v = xq[2*p], u = xq[2*p+1];
                short8 s;
                s[0]=(short)f2bf(v.x); s[1]=(short)f2bf(v.y);
                s[2]=(short)f2bf(v.z); s[3]=(short)f2bf(v.w);
                s[4]=(short)f2bf(u.x); s[5]=(short)f2bf(u.y);
                s[6]=(short)f2bf(u.z); s[7]=(short)f2bf(u.w);
                dst[p] = s;
            }
        }
    }
    if (k == 0) ws[0] = 0.0f;
}

// Two-pass MFMA-filtered VQ — LDS-shared B (canonical GEMM staging):
//  - R7 showed the loop is bound by per-wave private B reads from L2. Fix:
//    barrier-synced 128-entry chunks staged once to LDS by all 1024 threads;
//    16 waves consume via ds_read_b128 (granule-swizzled: 2 lanes/bank = free).
//  - per-block B traffic drops 16x; LDS read throughput replaces L2 latency.
//  - R9 = R8 with the qbuf/bsh LDS overlap fixed (the ONLY change).
//  - all fp chains / MFMA per-acc order / flags / rescore / loss verbatim R7
//    (the staged bytes are identical bf16 values -> bit-identical results).
__global__ __launch_bounds__(1024, 1) void vq_mfma(
        const float* __restrict__ in,
        const float* __restrict__ cb,
        float* __restrict__ ws,
        float* __restrict__ codes_f,
        float* __restrict__ out)
{
    extern __shared__ float smem[];
    float* xs    = smem;
    float* Atab  = smem + 16384;
    float* Ttab  = smem + 16640;                       // reused as dtab
    float* csq_s = smem + 16896;
    unsigned long long* keytab = (unsigned long long*)(smem + 17920);
    int* qcnt  = (int*)(smem + 18432);                 // [16]
    int* ovflp = (int*)(smem + 18448);
    unsigned short* qbuf = (unsigned short*)(smem + 18449);  // [16][QCAP], 1536 words
    unsigned short* bsh  = (unsigned short*)(smem + BSH_OFS);

    const int tid  = threadIdx.x;
    const int lane = tid & 63;
    const int w    = tid >> 6;                         // wave 0..15
    const int r    = lane & 15;
    const int g    = lane >> 4;
    const int wrow = w << 4;                           // 16 rows per wave
    const size_t rowBase = (size_t)blockIdx.x * RPB;
    const float* csq = ws + 256;
    const unsigned short* cbh = (const unsigned short*)(ws + 2048);
    float* loss_acc = ws;

    // ---- stage x once (swizzled), csq, init tabs ----
    {
        const float4* gx = (const float4*)(in + rowBase * DIM);
        #pragma unroll
        for (int i = 0; i < 4; ++i) {
            int idx = i * 1024 + tid;
            int row = idx >> 4, cj = idx & 15;
            float4 v = gx[idx];
            *(float4*)(xs + row * 64 + ((cj ^ (row & 15)) << 2)) = v;
        }
    }
    csq_s[tid] = csq[tid];                             // 1024 threads cover KCB
    if (tid < RPB) keytab[tid] = 0xFFFFFFFFFFFFFFFFull;
    if (tid < 16) qcnt[tid] = 0;
    if (tid == 0) *ovflp = 0;
    __syncthreads();

    // ---- per-row A (exact pairwise-8 order), S1, tau (row = tid; from LDS) ----
    if (tid < RPB) {
        const float* xr = xs + tid * 64;
        const int s = tid & 15;
        float A, S1;
        {
            #pragma clang fp contract(off)
            float racc[8], sacc[8];
            {
                float4 a = *(const float4*)(xr + ((0 ^ s) << 2));
                float4 b = *(const float4*)(xr + ((1 ^ s) << 2));
                racc[0]=a.x*a.x; racc[1]=a.y*a.y; racc[2]=a.z*a.z; racc[3]=a.w*a.w;
                racc[4]=b.x*b.x; racc[5]=b.y*b.y; racc[6]=b.z*b.z; racc[7]=b.w*b.w;
                sacc[0]=__builtin_fabsf(a.x); sacc[1]=__builtin_fabsf(a.y);
                sacc[2]=__builtin_fabsf(a.z); sacc[3]=__builtin_fabsf(a.w);
                sacc[4]=__builtin_fabsf(b.x); sacc[5]=__builtin_fabsf(b.y);
                sacc[6]=__builtin_fabsf(b.z); sacc[7]=__builtin_fabsf(b.w);
            }
            #pragma unroll
            for (int t = 1; t < 8; ++t) {
                float4 a = *(const float4*)(xr + (((2*t)   ^ s) << 2));
                float4 b = *(const float4*)(xr + (((2*t+1) ^ s) << 2));
                racc[0]+=a.x*a.x; racc[1]+=a.y*a.y; racc[2]+=a.z*a.z; racc[3]+=a.w*a.w;
                racc[4]+=b.x*b.x; racc[5]+=b.y*b.y; racc[6]+=b.z*b.z; racc[7]+=b.w*b.w;
                sacc[0]+=__builtin_fabsf(a.x); sacc[1]+=__builtin_fabsf(a.y);
                sacc[2]+=__builtin_fabsf(a.z); sacc[3]+=__builtin_fabsf(a.w);
                sacc[4]+=__builtin_fabsf(b.x); sacc[5]+=__builtin_fabsf(b.y);
                sacc[6]+=__builtin_fabsf(b.z); sacc[7]+=__builtin_fabsf(b.w);
            }
            A  = ((racc[0]+racc[1])+(racc[2]+racc[3]))
               + ((racc[4]+racc[5])+(racc[6]+racc[7]));
            S1 = ((sacc[0]+sacc[1])+(sacc[2]+sacc[3]))
               + ((sacc[4]+sacc[5])+(sacc[6]+sacc[7]));
        }
        Atab[tid] = A;
        Ttab[tid] = 1.52587890625e-05f * S1
                  + 4.76837158203125e-07f * (A + 1.0f)
                  + 1e-5f;                             // certified >= 2E (R2-R7 verified)
    }

    // ---- A-fragments (bf16 hi of x) from LDS (row = wrow + r) ----
    short8 af[2];
    #pragma unroll
    for (int h = 0; h < 2; ++h) {
        const int row = wrow + r;                      // row&15 == r
        const int cj = h*8 + g*2;
        float4 v0 = *(const float4*)(xs + row*64 + (((cj  ) ^ r) << 2));
        float4 v1 = *(const float4*)(xs + row*64 + (((cj+1) ^ r) << 2));
        short8 a;
        a[0]=(short)f2bf(v0.x); a[1]=(short)f2bf(v0.y);
        a[2]=(short)f2bf(v0.z); a[3]=(short)f2bf(v0.w);
        a[4]=(short)f2bf(v1.x); a[5]=(short)f2bf(v1.y);
        a[6]=(short)f2bf(v1.z); a[7]=(short)f2bf(v1.w);
        af[h] = a;
    }

    // stage helper: thread t moves one 16B granule; granule j of entry c goes
    // to slot j^(c&7)  (reads: 2 lanes/bank = conflict-free)
    const int sc = tid >> 3;                           // chunk-entry 0..127
    const int sj = tid & 7;                            // granule 0..7
    const int sdst = (sc << 6) + ((sj ^ (sc & 7)) << 3);   // ushort offset

    // ---- PASS 1: per-lane running max only ----
    float rm[4];
    #pragma unroll
    for (int s = 0; s < 4; ++s) rm[s] = -3.402823466e38f;

    #pragma unroll 1
    for (int nb = 0; nb < KCB; nb += BCH) {
        __syncthreads();                               // prev chunk fully consumed
        *(short8*)(bsh + sdst) =
            *(const short8*)(cbh + ((nb + sc) << 6) + (sj << 3));
        __syncthreads();                               // chunk visible to all

        f32x4 acc[8];
        #pragma unroll
        for (int nt = 0; nt < 8; ++nt) {
            const float ch = -0.5f * csq_s[nb + nt*16 + r];
            f32x4 c; c[0]=ch; c[1]=ch; c[2]=ch; c[3]=ch;
            const unsigned short* bp = bsh + ((nt*16 + r) << 6);
            short8 b0 = *(const short8*)(bp + (((g    ) ^ (r & 7)) << 3));  // h=0
            short8 b1 = *(const short8*)(bp + (((4 + g) ^ (r & 7)) << 3));  // h=1
            c = __builtin_amdgcn_mfma_f32_16x16x32_bf16(af[0], b0, c, 0, 0, 0);
            c = __builtin_amdgcn_mfma_f32_16x16x32_bf16(af[1], b1, c, 0, 0, 0);
            acc[nt] = c;
        }

        #pragma unroll
        for (int rg = 0; rg < 4; ++rg) {
            float cm = fmaxf(fmaxf(fmaxf(acc[0][rg], acc[1][rg]),
                                   fmaxf(acc[2][rg], acc[3][rg])),
                             fmaxf(fmaxf(acc[4][rg], acc[5][rg]),
                                   fmaxf(acc[6][rg], acc[7][rg])));
            rm[rg] = fmaxf(rm[rg], cm);
        }
    }

    // ---- one cross-lane reduce (over r bits) -> final per-row threshold ----
    float thr[4];
    #pragma unroll
    for (int s = 0; s < 4; ++s) {
        float cm = rm[s];
        cm = fmaxf(cm, __shfl_xor(cm, 1));
        cm = fmaxf(cm, __shfl_xor(cm, 2));
        cm = fmaxf(cm, __shfl_xor(cm, 4));
        cm = fmaxf(cm, __shfl_xor(cm, 8));
        thr[s] = cm - Ttab[wrow + g*4 + s];
    }

    // ---- PASS 2: recompute (bit-identical) + ballot-compacted flagging ----
    #pragma unroll 1
    for (int nb = 0; nb < KCB; nb += BCH) {
        __syncthreads();
        *(short8*)(bsh + sdst) =
            *(const short8*)(cbh + ((nb + sc) << 6) + (sj << 3));
        __syncthreads();

        f32x4 acc[8];
        #pragma unroll
        for (int nt = 0; nt < 8; ++nt) {
            const float ch = -0.5f * csq_s[nb + nt*16 + r];
            f32x4 c; c[0]=ch; c[1]=ch; c[2]=ch; c[3]=ch;
            const unsigned short* bp = bsh + ((nt*16 + r) << 6);
            short8 b0 = *(const short8*)(bp + (((g    ) ^ (r & 7)) << 3));
            short8 b1 = *(const short8*)(bp + (((4 + g) ^ (r & 7)) << 3));
            c = __builtin_amdgcn_mfma_f32_16x16x32_bf16(af[0], b0, c, 0, 0, 0);
            c = __builtin_amdgcn_mfma_f32_16x16x32_bf16(af[1], b1, c, 0, 0, 0);
            acc[nt] = c;
        }

        #pragma unroll
        for (int rg = 0; rg < 4; ++rg) {
            const float th = thr[rg];
            bool fl[8]; bool any = false;
            #pragma unroll
            for (int nt = 0; nt < 8; ++nt) { fl[nt] = acc[nt][rg] >= th; any |= fl[nt]; }
            if (__ballot(any)) {                       // uniform coarse skip
                const int rowLocal = g*4 + rg;         // 0..15 within wave
                #pragma unroll
                for (int nt = 0; nt < 8; ++nt) {
                    unsigned long long m = __ballot(fl[nt]);
                    if (m) {
                        int base = 0;
                        if (lane == 0) base = atomicAdd(&qcnt[w], (int)__popcll(m));
                        base = __builtin_amdgcn_readfirstlane(base);
                        if (fl[nt]) {
                            int pos = base + (int)__popcll(m & ((1ull << lane) - 1ull));
                            if (pos < QCAP)
                                qbuf[w * QCAP + pos] =
                                    (unsigned short)((rowLocal << 10) | (nb + nt*16 + r));
                            else *ovflp = 1;
                        }
                    }
                }
            }
        }
    }

    // ---- batched exact rescore (x from LDS, bit-identical) + atomicMin merge ----
    const int cnt  = qcnt[w];
    const int cmax = cnt < QCAP ? cnt : QCAP;
    for (int base = 0; base < cmax; base += 64) {
        const int i = base + lane;
        if (i < cmax) {
            const int item = qbuf[w * QCAP + i];
            const int row = wrow + (item >> 10);
            const int n = item & 1023;
            const float* xr = xs + row * 64;
            const int sr = row & 15;
            const float4* e4 = (const float4*)(cb + ((size_t)n << 6));
            float mm = 0.f;
            #pragma unroll
            for (int j = 0; j < 16; ++j) {
                float4 xq = *(const float4*)(xr + ((j ^ sr) << 2));
                float4 eq = e4[j];
                mm = __builtin_fmaf(xq.x, eq.x, mm);
                mm = __builtin_fmaf(xq.y, eq.y, mm);
                mm = __builtin_fmaf(xq.z, eq.z, mm);
                mm = __builtin_fmaf(xq.w, eq.w, mm);
            }
            float dd;
            {
                #pragma clang fp contract(off)
                dd = (Atab[row] - 2.0f * mm) + csq_s[n];
            }
            unsigned long long key =
                ((unsigned long long)__float_as_uint(dd) << 32) | (unsigned)n;
            atomicMin(&keytab[row], key);
        }
    }
    __syncthreads();

    // ---- per-row result, overflow fallback, code publish ----
    float* dtab = Ttab;                                // Ttab dead past thr computation
    if (tid < RPB) {
        unsigned long long kk = keytab[tid];
        int   kb = (int)(kk & 1023u);
        float db = __uint_as_float((unsigned)(kk >> 32));
        if (*ovflp) {   // practically unreachable; exact full scan
            const float* xr = in + (rowBase + tid) * (size_t)DIM;
            float dmin = 3.402823466e38f; int kmin = 0;
            for (int n = 0; n < KCB; ++n) {
                const float* eg = cb + ((size_t)n << 6);
                float mmv = 0.f;
                for (int j = 0; j < 64; ++j) mmv = __builtin_fmaf(xr[j], eg[j], mmv);
                float ddv;
                {
                    #pragma clang fp contract(off)
                    ddv = (Atab[tid] - 2.0f * mmv) + csq_s[n];
                }
                if (ddv < dmin) { dmin = ddv; kmin = n; }
            }
            db = dmin; kb = kmin;
        }
        dtab[tid] = db;
        codes_f[rowBase + tid] = (float)kb;
        keytab[tid] = (unsigned long long)(unsigned)kb;   // publish code for ST pass
    }
    __syncthreads();

    // ---- fused straight-through write: st = x + (q - x), x from LDS ----
    {
        float4* gout = (float4*)(out + rowBase * DIM);
        #pragma unroll
        for (int i = 0; i < 4; ++i) {
            int idx = i * 1024 + tid;
            int row = idx >> 4, cj = idx & 15;
            int code = (int)keytab[row];
            float4 qv = *(const float4*)(cb + ((size_t)code << 6) + (cj << 2));
            float4 xv = *(const float4*)(xs + row * 64 + ((cj ^ (row & 15)) << 2));
            float4 st;
            {
                #pragma clang fp contract(off)
                st.x = xv.x + (qv.x - xv.x);
                st.y = xv.y + (qv.y - xv.y);
                st.z = xv.z + (qv.z - xv.z);
                st.w = xv.w + (qv.w - xv.w);
            }
            gout[idx] = st;
        }
    }

    // ---- loss partial (identical 256-leaf tree) ----
    __syncthreads();
    #pragma unroll
    for (int s = 128; s > 0; s >>= 1) {
        if (tid < s) dtab[tid] += dtab[tid + s];
        __syncthreads();
    }
    if (tid == 0) atomicAdd(loss_acc, dtab[0]);
}

// ===================== fallback: R1 scalar kernel (used only if ws too small) ==========
#define OLD_SMEM_WORDS 20480
#define OLD_SMEM_BYTES (OLD_SMEM_WORDS * 4)

__global__ __launch_bounds__(512, 4) void vq_main_old(
        const float* __restrict__ in,
        const float* __restrict__ cb,
        const float* __restrict__ csq,
        float* __restrict__ codes_f,
        float* __restrict__ out,
        float* __restrict__ loss_acc)
{
    extern __shared__ float smem[];
    float* xs    = smem;
    float* dtab  = smem + 16384;
    int*   ktab  = (int*)(smem + 18432);

    const int tid  = threadIdx.x;
    const int lane = tid & 63;
    const int q    = __builtin_amdgcn_readfirstlane(tid >> 6);
    const size_t rowBase = (size_t)blockIdx.x * RPB;

    {
        const float4* gx = (const float4*)(in + rowBase * DIM);
        #pragma unroll
        for (int i = 0; i < 8; ++i) {
            int idx = i * 512 + tid;
            int row = idx >> 4, cj = idx & 15;
            float4 v = gx[idx];
            *(float4*)(xs + row * 64 + ((cj ^ (row & 15)) << 2)) = v;
        }
    }
    __syncthreads();

    float A[4];
    #pragma unroll
    for (int ri = 0; ri < 4; ++ri) {
        const int row = lane + (ri << 6);
        float xv[64];
        #pragma unroll
        for (int cj = 0; cj < 16; ++cj) {
            float4 v = *(const float4*)(xs + row * 64 + ((cj ^ (lane & 15)) << 2));
            xv[cj*4+0]=v.x; xv[cj*4+1]=v.y; xv[cj*4+2]=v.z; xv[cj*4+3]=v.w;
        }
        {
            #pragma clang fp contract(off)
            float racc[8];
            #pragma unroll
            for (int j = 0; j < 8; ++j) racc[j] = xv[j] * xv[j];
            #pragma unroll
            for (int t = 1; t < 8; ++t) {
                #pragma unroll
                for (int j = 0; j < 8; ++j) racc[j] += xv[8*t+j] * xv[8*t+j];
            }
            A[ri] = ((racc[0] + racc[1]) + (racc[2] + racc[3]))
                  + ((racc[4] + racc[5]) + (racc[6] + racc[7]));
        }
    }

    const float* cbq   = cb  + ((size_t)q << 13);
    const float* csq_q = csq + (q << 7);
    float dmin[4] = {3.402823466e38f, 3.402823466e38f, 3.402823466e38f, 3.402823466e38f};
    int   kmin[4] = {0, 0, 0, 0};
    const int xb = lane * 64;

    #pragma unroll 1
    for (int ke = 0; ke < 128; ke += 16) {
        float m[4][16];
        #pragma unroll
        for (int ri = 0; ri < 4; ++ri)
            #pragma unroll
            for (int e = 0; e < 16; ++e) m[ri][e] = 0.0f;

        #pragma unroll 1
        for (int jb = 0; jb < 64; jb += 4) {
            const int slot4 = ((jb >> 2) ^ (lane & 15)) << 2;
            float4 a0 = *(const float4*)(xs + xb +         slot4);
            float4 a1 = *(const float4*)(xs + xb +  4096 + slot4);
            float4 a2 = *(const float4*)(xs + xb +  8192 + slot4);
            float4 a3 = *(const float4*)(xs + xb + 12288 + slot4);
            #pragma unroll
            for (int e = 0; e < 16; ++e) {
                float4 ev = *(const float4*)(cbq + ((ke + e) << 6) + jb);
                m[0][e] = __builtin_fmaf(a0.x, ev.x, m[0][e]);
                m[0][e] = __builtin_fmaf(a0.y, ev.y, m[0][e]);
                m[0][e] = __builtin_fmaf(a0.z, ev.z, m[0][e]);
                m[0][e] = __builtin_fmaf(a0.w, ev.w, m[0][e]);
                m[1][e] = __builtin_fmaf(a1.x, ev.x, m[1][e]);
                m[1][e] = __builtin_fmaf(a1.y, ev.y, m[1][e]);
                m[1][e] = __builtin_fmaf(a1.z, ev.z, m[1][e]);
                m[1][e] = __builtin_fmaf(a1.w, ev.w, m[1][e]);
                m[2][e] = __builtin_fmaf(a2.x, ev.x, m[2][e]);
                m[2][e] = __builtin_fmaf(a2.y, ev.y, m[2][e]);
                m[2][e] = __builtin_fmaf(a2.z, ev.z, m[2][e]);
                m[2][e] = __builtin_fmaf(a2.w, ev.w, m[2][e]);
                m[3][e] = __builtin_fmaf(a3.x, ev.x, m[3][e]);
                m[3][e] = __builtin_fmaf(a3.y, ev.y, m[3][e]);
                m[3][e] = __builtin_fmaf(a3.z, ev.z, m[3][e]);
                m[3][e] = __builtin_fmaf(a3.w, ev.w, m[3][e]);
            }
        }

        #pragma unroll
        for (int e = 0; e < 16; ++e) {
            float cse = csq_q[ke + e];
            int gk = (q << 7) + ke + e;
            #pragma unroll
            for (int ri = 0; ri < 4; ++ri) {
                float d;
                {
                    #pragma clang fp contract(off)
                    d = (A[ri] - 2.0f * m[ri][e]) + cse;
                }
                if (d < dmin[ri]) { dmin[ri] = d; kmin[ri] = gk; }
            }
        }
    }

    #pragma unroll
    for (int ri = 0; ri < 4; ++ri) {
        int row = lane + (ri << 6);
        dtab[row * 8 + q] = dmin[ri];
        ktab[row * 8 + q] = kmin[ri];
    }
    __syncthreads();

    float db = 0.0f;
    if (tid < RPB) {
        db = dtab[tid * 8];
        int kb = ktab[tid * 8];
        #pragma unroll
        for (int qq = 1; qq < 8; ++qq) {
            float dq = dtab[tid * 8 + qq];
            int   kq = ktab[tid * 8 + qq];
            if (dq < db) { db = dq; kb = kq; }
        }
        ktab[tid * 8] = kb;
        codes_f[rowBase + tid] = (float)kb;
    }
    __syncthreads();

    {
        float4* gout = (float4*)(out + rowBase * DIM);
        #pragma unroll
        for (int i = 0; i < 8; ++i) {
            int idx = i * 512 + tid;
            int row = idx >> 4, cj = idx & 15;
            int code = ktab[row * 8];
            float4 qv = *(const float4*)(cb + ((size_t)code << 6) + (cj << 2));
            float4 xv = *(const float4*)(xs + row * 64 + ((cj ^ (row & 15)) << 2));
            float4 st;
            {
                #pragma clang fp contract(off)
                st.x = xv.x + (qv.x - xv.x);
                st.y = xv.y + (qv.y - xv.y);
                st.z = xv.z + (qv.z - xv.z);
                st.w = xv.w + (qv.w - xv.w);
            }
            gout[idx] = st;
        }
    }

    if (tid < RPB) dtab[tid] = db;
    __syncthreads();
    #pragma unroll
    for (int s = 128; s > 0; s >>= 1) {
        if (tid < s) dtab[tid] += dtab[tid + s];
        __syncthreads();
    }
    if (tid == 0) atomicAdd(loss_acc, dtab[0]);
}

__global__ void vq_final(const float* __restrict__ ws, float* __restrict__ loss_out) {
    loss_out[0] = 1.25f * ws[0] / 8388608.0f;
}

extern "C" void kernel_launch(void* const* d_in, const int* in_sizes, int n_in,
                              void* d_out, int out_size, void* d_ws, size_t ws_size,
                              hipStream_t stream) {
    const float* in = (const float*)d_in[0];   // (32,4096,64) fp32
    const float* cb = (const float*)d_in[1];   // (1024,64)    fp32
    float* out     = (float*)d_out;
    float* codes_f = out + 8388608;
    float* loss_p  = out + 8519680;
    float* ws      = (float*)d_ws;

    const int big = (ws_size >= (size_t)WS_NEED_BYTES) ? 1 : 0;

    vq_prep<<<16, 64, 0, stream>>>(cb, ws, big);
    if (big) {
        hipFuncSetAttribute((const void*)vq_mfma,
                            hipFuncAttributeMaxDynamicSharedMemorySize, SMEM_BYTES);
        vq_mfma<<<512, 1024, SMEM_BYTES, stream>>>(in, cb, ws, codes_f, out);
    } else {
        hipFuncSetAttribute((const void*)vq_main_old,
                            hipFuncAttributeMaxDynamicSharedMemorySize, OLD_SMEM_BYTES);
        vq_main_old<<<512, 512, OLD_SMEM_BYTES, stream>>>(in, cb, ws + 256, codes_f, out, ws);
    }
    vq_final<<<1, 1, 0, stream>>>(ws, loss_p);
}